// Round 1
// baseline (2621.617 us; speedup 1.0000x reference)
//
#include <hip/hip_runtime.h>

// Jamba sparse MoE: T=32768 tokens, D=1024, F=2048, E=16, top-2.
// Pipeline: transpose/cast weights -> router (fused x->bf16) -> scan ->
// permutation -> grouped gate/up GEMM (fused SiLU*up) -> grouped down GEMM
// with weighted atomic scatter into out.

#define T_ 32768
#define D_ 1024
#define F_ 2048
#define E_ 16
#define P_ 65536      // T_ * TOP_K
#define MAXTILES 528  // sum ceil(n_e/128) <= P/128 + E - 1

typedef __bf16 bf16x8 __attribute__((ext_vector_type(8)));
typedef float floatx4 __attribute__((ext_vector_type(4)));
typedef unsigned short bfu;  // raw bf16 bits storage

// ws layout (bytes)
#define O_XB 0ull                       // x bf16            [T, D]    64 MB
#define O_WG 67108864ull                // gate^T bf16       [E][F][D] 64 MB
#define O_WU 134217728ull               // up^T bf16         [E][F][D] 64 MB
#define O_WD 201326592ull               // down^T bf16       [E][D][F] 64 MB
#define O_H  268435456ull               // h bf16            [P, F]   256 MB
#define O_CW 536870912ull               // combine weight    [P] f32
#define O_EI 537133056ull               // expert idx        [P] i32
#define O_PM 537395200ull               // perm pos->pairid  [P] i32
#define O_MT 537657344ull               // meta ints (counts/cursor/offsets/tiles)
// meta ints: [0..15]=counts [16..31]=cursor [32..48]=offsets [49]=ntiles
//            [64..591]=tile_expert [592..1119]=tile_row

__device__ __forceinline__ unsigned short f2bf(float f) {
  unsigned int u = __float_as_uint(f);
  u = u + 0x7fffu + ((u >> 16) & 1u);  // RNE
  return (unsigned short)(u >> 16);
}

__device__ __forceinline__ void gload16(const void* g, void* l) {
  __builtin_amdgcn_global_load_lds(
      (const __attribute__((address_space(1))) unsigned int*)g,
      (__attribute__((address_space(3))) unsigned int*)l, 16, 0, 0);
}

// src [E][R][C] fp32 -> dst [E][C][R] bf16
__global__ __launch_bounds__(256) void transpose_cast_kernel(
    const float* __restrict__ src, bfu* __restrict__ dst, int R, int C) {
  __shared__ float tile[64][65];
  const int e = blockIdx.z;
  const int r0 = blockIdx.y * 64, c0 = blockIdx.x * 64;
  const size_t base = (size_t)e * R * C;
  const int tid = threadIdx.x;
  const int rr = tid >> 4;
  const int cc = (tid & 15) * 4;
  const float* sp = src + base + (size_t)(r0 + rr) * C + (c0 + cc);
#pragma unroll
  for (int i = 0; i < 4; ++i) {
    float4 v = *(const float4*)(sp + (size_t)(i * 16) * C);
    tile[rr + i * 16][cc + 0] = v.x;
    tile[rr + i * 16][cc + 1] = v.y;
    tile[rr + i * 16][cc + 2] = v.z;
    tile[rr + i * 16][cc + 3] = v.w;
  }
  __syncthreads();
  const int oc = tid >> 2;
  const int sg = (tid & 3) * 16;
  union { bfu b[16]; uint4 q[2]; } u;
#pragma unroll
  for (int j = 0; j < 16; ++j) u.b[j] = f2bf(tile[sg + j][oc]);
  bfu* dp = dst + base + (size_t)(c0 + oc) * R + (r0 + sg);
  ((uint4*)dp)[0] = u.q[0];
  ((uint4*)dp)[1] = u.q[1];
}

// one wave per token: x->bf16, fp32 logits -> d_out tail, softmax, top-2
__global__ __launch_bounds__(64) void router_kernel(
    const float* __restrict__ x, const float* __restrict__ rw,
    bfu* __restrict__ xb, float* __restrict__ logits,
    float* __restrict__ cw, int* __restrict__ eidx, int* __restrict__ meta) {
  const int t = blockIdx.x, lane = threadIdx.x;
  const float* xp = x + (size_t)t * D_ + lane * 16;
  float xv[16];
#pragma unroll
  for (int i = 0; i < 4; ++i) {
    float4 v = ((const float4*)xp)[i];
    xv[i * 4 + 0] = v.x; xv[i * 4 + 1] = v.y;
    xv[i * 4 + 2] = v.z; xv[i * 4 + 3] = v.w;
  }
  union { bfu b[16]; uint4 q[2]; } u;
#pragma unroll
  for (int i = 0; i < 16; ++i) u.b[i] = f2bf(xv[i]);
  uint4* xbp = (uint4*)(xb + (size_t)t * D_ + lane * 16);
  xbp[0] = u.q[0];
  xbp[1] = u.q[1];

  float l[16];
#pragma unroll
  for (int e = 0; e < 16; ++e) {
    const float* wp = rw + (size_t)e * D_ + lane * 16;
    float s = 0.f;
#pragma unroll
    for (int i = 0; i < 4; ++i) {
      float4 w = ((const float4*)wp)[i];
      s += xv[i * 4 + 0] * w.x + xv[i * 4 + 1] * w.y +
           xv[i * 4 + 2] * w.z + xv[i * 4 + 3] * w.w;
    }
#pragma unroll
    for (int off = 32; off; off >>= 1) s += __shfl_xor(s, off);
    l[e] = s;
  }
  float m = l[0];
#pragma unroll
  for (int e = 1; e < 16; ++e) m = fmaxf(m, l[e]);
  float p[16], sum = 0.f;
#pragma unroll
  for (int e = 0; e < 16; ++e) { p[e] = expf(l[e] - m); sum += p[e]; }
  int e0 = 0; float b0 = p[0];
#pragma unroll
  for (int e = 1; e < 16; ++e) if (p[e] > b0) { b0 = p[e]; e0 = e; }
  int e1 = -1; float b1 = -1.f;
#pragma unroll
  for (int e = 0; e < 16; ++e) if (e != e0 && p[e] > b1) { b1 = p[e]; e1 = e; }
  if (lane < 16) logits[(size_t)t * 16 + lane] = l[lane];
  if (lane == 0) {
    float inv = 1.f / sum;
    cw[t * 2 + 0] = b0 * inv;
    cw[t * 2 + 1] = b1 * inv;
    eidx[t * 2 + 0] = e0;
    eidx[t * 2 + 1] = e1;
    atomicAdd(&meta[e0], 1);
    atomicAdd(&meta[e1], 1);
  }
}

__global__ void scan_kernel(int* __restrict__ meta) {
  if (threadIdx.x != 0) return;
  int off = 0, nt = 0;
  for (int e = 0; e < 16; ++e) {
    meta[32 + e] = off;
    int n = meta[e];
    for (int r = 0; r < n; r += 128) {
      meta[64 + nt] = e;
      meta[592 + nt] = off + r;
      ++nt;
    }
    off += n;
  }
  meta[48] = off;
  meta[49] = nt;
}

__global__ __launch_bounds__(256) void perm_kernel(
    const int* __restrict__ eidx, int* __restrict__ meta, int* __restrict__ perm) {
  const int p = blockIdx.x * 256 + threadIdx.x;
  const int e = eidx[p];
  const int pos = atomicAdd(&meta[16 + e], 1);
  perm[meta[32 + e] + pos] = p;
}

// grouped gate/up GEMM: h[p, f] = silu(x@Wg) * (x@Wu), 128x128 tile, BK=32
__global__ __launch_bounds__(256, 2) void gateup_kernel(
    const bfu* __restrict__ xb, const bfu* __restrict__ wg,
    const bfu* __restrict__ wu, bfu* __restrict__ h,
    const int* __restrict__ perm, const int* __restrict__ meta) {
  __shared__ bfu As[128 * 32];
  __shared__ bfu Bg[128 * 32];
  __shared__ bfu Bu[128 * 32];
  __shared__ int rowtok[128];

  const int tile = blockIdx.y;
  if (tile >= meta[49]) return;
  const int e = meta[64 + tile];
  const int row0 = meta[592 + tile];
  const int nvalid = meta[33 + e] - row0;
  const int n0 = blockIdx.x * 128;
  const int tid = threadIdx.x, lane = tid & 63, wave = tid >> 6;

  if (tid < 128) {
    int r = tid < nvalid ? tid : (nvalid - 1);
    rowtok[tid] = perm[row0 + r] >> 1;
  }
  __syncthreads();

  const int ldr = wave * 32 + (lane >> 2);
  const int kseg = (lane & 3) * 8;
  const bfu* ap1 = xb + (size_t)rowtok[ldr] * D_ + kseg;
  const bfu* ap2 = xb + (size_t)rowtok[ldr + 16] * D_ + kseg;
  const size_t wb = (size_t)e * F_ * D_;
  const bfu* gp1 = wg + wb + (size_t)(n0 + ldr) * D_ + kseg;
  const bfu* gp2 = gp1 + (size_t)16 * D_;
  const bfu* up1 = wu + wb + (size_t)(n0 + ldr) * D_ + kseg;
  const bfu* up2 = up1 + (size_t)16 * D_;
  bfu* al1 = As + (wave * 32) * 32;
  bfu* al2 = As + (wave * 32 + 16) * 32;
  bfu* gl1 = Bg + (wave * 32) * 32;
  bfu* gl2 = Bg + (wave * 32 + 16) * 32;
  bfu* ul1 = Bu + (wave * 32) * 32;
  bfu* ul2 = Bu + (wave * 32 + 16) * 32;

  const int wm = (wave >> 1) * 64, wn = (wave & 1) * 64;
  const int fro = (lane & 15) * 32 + (lane >> 4) * 8;
  const bf16x8* afp = (const bf16x8*)(As + wm * 32 + fro);
  const bf16x8* bgp = (const bf16x8*)(Bg + wn * 32 + fro);
  const bf16x8* bup = (const bf16x8*)(Bu + wn * 32 + fro);

  floatx4 accg[4][4] = {};
  floatx4 accu[4][4] = {};

  for (int k0 = 0; k0 < D_; k0 += 32) {
    gload16(ap1 + k0, al1);
    gload16(ap2 + k0, al2);
    gload16(gp1 + k0, gl1);
    gload16(gp2 + k0, gl2);
    gload16(up1 + k0, ul1);
    gload16(up2 + k0, ul2);
    __syncthreads();
    bf16x8 af[4], bgf[4], buf_[4];
#pragma unroll
    for (int i = 0; i < 4; ++i) {
      af[i] = afp[i * 64];
      bgf[i] = bgp[i * 64];
      buf_[i] = bup[i * 64];
    }
#pragma unroll
    for (int mi = 0; mi < 4; ++mi)
#pragma unroll
      for (int ni = 0; ni < 4; ++ni) {
        accg[mi][ni] = __builtin_amdgcn_mfma_f32_16x16x32_bf16(
            af[mi], bgf[ni], accg[mi][ni], 0, 0, 0);
        accu[mi][ni] = __builtin_amdgcn_mfma_f32_16x16x32_bf16(
            af[mi], buf_[ni], accu[mi][ni], 0, 0, 0);
      }
    __syncthreads();
  }

  // epilogue: silu(g)*u -> bf16, repack 16x64 slabs through LDS for 16B stores
  bfu* slab = As + wave * 1024;  // wave-private 16x64 bf16
  const int sq = lane >> 4, sc = lane & 15;
  const int orow = lane >> 2, osg = (lane & 3) * 16;
#pragma unroll
  for (int mi = 0; mi < 4; ++mi) {
    __syncthreads();
#pragma unroll
    for (int ni = 0; ni < 4; ++ni) {
      floatx4 g = accg[mi][ni], v = accu[mi][ni];
#pragma unroll
      for (int i = 0; i < 4; ++i) {
        float gv = g[i];
        float hv = (gv / (1.f + __expf(-gv))) * v[i];
        slab[(sq * 4 + i) * 64 + ni * 16 + sc] = f2bf(hv);
      }
    }
    __syncthreads();
    const int prow = wm + mi * 16 + orow;
    if (prow < nvalid) {
      bfu* hp = h + (size_t)(row0 + prow) * F_ + (n0 + wn + osg);
      uint4 q0 = *(const uint4*)(slab + orow * 64 + osg);
      uint4 q1 = *(const uint4*)(slab + orow * 64 + osg + 8);
      ((uint4*)hp)[0] = q0;
      ((uint4*)hp)[1] = q1;
    }
  }
}

// grouped down GEMM: out[tok, d] += w * (h @ Wd), atomic scatter
__global__ __launch_bounds__(256, 2) void down_kernel(
    const bfu* __restrict__ h, const bfu* __restrict__ wd,
    float* __restrict__ out, const float* __restrict__ cw,
    const int* __restrict__ perm, const int* __restrict__ meta) {
  __shared__ bfu As[128 * 32];
  __shared__ bfu Bs[128 * 32];
  __shared__ int rtok[128];
  __shared__ float rwt[128];

  const int tile = blockIdx.y;
  if (tile >= meta[49]) return;
  const int e = meta[64 + tile];
  const int row0 = meta[592 + tile];
  const int nvalid = meta[33 + e] - row0;
  const int n0 = blockIdx.x * 128;
  const int tid = threadIdx.x, lane = tid & 63, wave = tid >> 6;

  if (tid < 128) {
    if (tid < nvalid) {
      int pr = perm[row0 + tid];
      rtok[tid] = pr >> 1;
      rwt[tid] = cw[pr];
    } else {
      rtok[tid] = 0;
      rwt[tid] = 0.f;
    }
  }
  __syncthreads();

  const int ldr = wave * 32 + (lane >> 2);
  const int kseg = (lane & 3) * 8;
  const int r1 = min(ldr, nvalid - 1);
  const int r2 = min(ldr + 16, nvalid - 1);
  const bfu* ap1 = h + (size_t)(row0 + r1) * F_ + kseg;
  const bfu* ap2 = h + (size_t)(row0 + r2) * F_ + kseg;
  const bfu* bp1 = wd + (size_t)e * D_ * F_ + (size_t)(n0 + ldr) * F_ + kseg;
  const bfu* bp2 = bp1 + (size_t)16 * F_;
  bfu* al1 = As + (wave * 32) * 32;
  bfu* al2 = As + (wave * 32 + 16) * 32;
  bfu* bl1 = Bs + (wave * 32) * 32;
  bfu* bl2 = Bs + (wave * 32 + 16) * 32;

  const int wm = (wave >> 1) * 64, wn = (wave & 1) * 64;
  const int fro = (lane & 15) * 32 + (lane >> 4) * 8;
  const bf16x8* afp = (const bf16x8*)(As + wm * 32 + fro);
  const bf16x8* bfp = (const bf16x8*)(Bs + wn * 32 + fro);

  floatx4 acc[4][4] = {};
  for (int k0 = 0; k0 < F_; k0 += 32) {
    gload16(ap1 + k0, al1);
    gload16(ap2 + k0, al2);
    gload16(bp1 + k0, bl1);
    gload16(bp2 + k0, bl2);
    __syncthreads();
    bf16x8 af[4], bf_[4];
#pragma unroll
    for (int i = 0; i < 4; ++i) { af[i] = afp[i * 64]; bf_[i] = bfp[i * 64]; }
#pragma unroll
    for (int mi = 0; mi < 4; ++mi)
#pragma unroll
      for (int ni = 0; ni < 4; ++ni)
        acc[mi][ni] = __builtin_amdgcn_mfma_f32_16x16x32_bf16(
            af[mi], bf_[ni], acc[mi][ni], 0, 0, 0);
    __syncthreads();
  }

  const int sq = lane >> 4, sc = lane & 15;
#pragma unroll
  for (int mi = 0; mi < 4; ++mi) {
#pragma unroll
    for (int i = 0; i < 4; ++i) {
      const int r = wm + mi * 16 + sq * 4 + i;
      const float w = rwt[r];
      if (w != 0.f) {
        const int tok = rtok[r];
        float* op = out + (size_t)tok * D_ + n0 + wn + sc;
#pragma unroll
        for (int ni = 0; ni < 4; ++ni)
          atomicAdd(op + ni * 16, w * acc[mi][ni][i]);
      }
    }
  }
}

extern "C" void kernel_launch(void* const* d_in, const int* in_sizes, int n_in,
                              void* d_out, int out_size, void* d_ws, size_t ws_size,
                              hipStream_t stream) {
  const float* x  = (const float*)d_in[0];
  const float* rw = (const float*)d_in[1];
  const float* gw = (const float*)d_in[2];
  const float* uw = (const float*)d_in[3];
  const float* dw = (const float*)d_in[4];
  float* out = (float*)d_out;
  float* logits = out + (size_t)T_ * D_;

  char* ws = (char*)d_ws;
  bfu* xb  = (bfu*)(ws + O_XB);
  bfu* wgt = (bfu*)(ws + O_WG);
  bfu* wut = (bfu*)(ws + O_WU);
  bfu* wdt = (bfu*)(ws + O_WD);
  bfu* hb  = (bfu*)(ws + O_H);
  float* cwp = (float*)(ws + O_CW);
  int* eip  = (int*)(ws + O_EI);
  int* perm = (int*)(ws + O_PM);
  int* meta = (int*)(ws + O_MT);

  // zero out accumulator region + counts/cursors
  hipMemsetAsync(out, 0, (size_t)T_ * D_ * sizeof(float), stream);
  hipMemsetAsync(meta, 0, 128, stream);

  // weight transpose+cast: gate/up [D,F]->[F,D], down [F,D]->[D,F]
  transpose_cast_kernel<<<dim3(F_ / 64, D_ / 64, E_), 256, 0, stream>>>(gw, wgt, D_, F_);
  transpose_cast_kernel<<<dim3(F_ / 64, D_ / 64, E_), 256, 0, stream>>>(uw, wut, D_, F_);
  transpose_cast_kernel<<<dim3(D_ / 64, F_ / 64, E_), 256, 0, stream>>>(dw, wdt, F_, D_);

  router_kernel<<<T_, 64, 0, stream>>>(x, rw, xb, logits, cwp, eip, meta);
  scan_kernel<<<1, 64, 0, stream>>>(meta);
  perm_kernel<<<P_ / 256, 256, 0, stream>>>(eip, meta, perm);

  gateup_kernel<<<dim3(F_ / 128, MAXTILES), 256, 0, stream>>>(xb, wgt, wut, hb, perm, meta);
  down_kernel<<<dim3(D_ / 128, MAXTILES), 256, 0, stream>>>(hb, wdt, out, cwp, perm, meta);
}

// Round 2
// 1819.562 us; speedup vs baseline: 1.4408x; 1.4408x over previous
//
#include <hip/hip_runtime.h>

// Jamba sparse MoE: T=32768 tokens, D=1024, F=2048, E=16, top-2.
// Pipeline: transpose/cast weights -> router (fused x->bf16, LDS-aggregated
// counts) -> scan -> perm (ballot-ranked, block-aggregated cursors) ->
// grouped gate/up GEMM (fused SiLU*up) -> grouped down GEMM with weighted
// atomic scatter into out.
//
// R1 lesson: 131072 device atomics into ONE cacheline (meta[0..15]) cost
// 768us (5.9ns/op serialized). Counters/cursors now padded to 1 line each
// (stride 32 ints) and aggregated per-block in LDS first.

#define T_ 32768
#define D_ 1024
#define F_ 2048
#define E_ 16
#define P_ 65536      // T_ * TOP_K
#define MAXTILES 528  // sum ceil(n_e/128) <= P/128 + E - 1

typedef __bf16 bf16x8 __attribute__((ext_vector_type(8)));
typedef float floatx4 __attribute__((ext_vector_type(4)));
typedef unsigned short bfu;  // raw bf16 bits storage

// ws layout (bytes)
#define O_XB 0ull                       // x bf16            [T, D]    64 MB
#define O_WG 67108864ull                // gate^T bf16       [E][F][D] 64 MB
#define O_WU 134217728ull               // up^T bf16         [E][F][D] 64 MB
#define O_WD 201326592ull               // down^T bf16       [E][D][F] 64 MB
#define O_H  268435456ull               // h bf16            [P, F]   256 MB
#define O_CW 536870912ull               // combine weight    [P] f32
#define O_EI 537133056ull               // expert idx        [P] i32
#define O_PM 537395200ull               // perm pos->pairid  [P] i32
#define O_MT 537657344ull               // meta ints
// meta int layout (cacheline-padded hot counters):
//   counts:  meta[e*32]            e<16   (one 128B line per counter)
//   cursors: meta[512 + e*32]      e<16
//   offsets: meta[1024 + e]        e<17   (exclusive scan, [16]=total)
//   ntiles:  meta[1041]
//   tile_e:  meta[1056 + i]        i<528
//   tile_r:  meta[1600 + i]        i<528

__device__ __forceinline__ unsigned short f2bf(float f) {
  unsigned int u = __float_as_uint(f);
  u = u + 0x7fffu + ((u >> 16) & 1u);  // RNE
  return (unsigned short)(u >> 16);
}

__device__ __forceinline__ void gload16(const void* g, void* l) {
  __builtin_amdgcn_global_load_lds(
      (const __attribute__((address_space(1))) unsigned int*)g,
      (__attribute__((address_space(3))) unsigned int*)l, 16, 0, 0);
}

// src [E][R][C] fp32 -> dst [E][C][R] bf16
__global__ __launch_bounds__(256) void transpose_cast_kernel(
    const float* __restrict__ src, bfu* __restrict__ dst, int R, int C) {
  __shared__ float tile[64][65];
  const int e = blockIdx.z;
  const int r0 = blockIdx.y * 64, c0 = blockIdx.x * 64;
  const size_t base = (size_t)e * R * C;
  const int tid = threadIdx.x;
  const int rr = tid >> 4;
  const int cc = (tid & 15) * 4;
  const float* sp = src + base + (size_t)(r0 + rr) * C + (c0 + cc);
#pragma unroll
  for (int i = 0; i < 4; ++i) {
    float4 v = *(const float4*)(sp + (size_t)(i * 16) * C);
    tile[rr + i * 16][cc + 0] = v.x;
    tile[rr + i * 16][cc + 1] = v.y;
    tile[rr + i * 16][cc + 2] = v.z;
    tile[rr + i * 16][cc + 3] = v.w;
  }
  __syncthreads();
  const int oc = tid >> 2;
  const int sg = (tid & 3) * 16;
  union { bfu b[16]; uint4 q[2]; } u;
#pragma unroll
  for (int j = 0; j < 16; ++j) u.b[j] = f2bf(tile[sg + j][oc]);
  bfu* dp = dst + base + (size_t)(c0 + oc) * R + (r0 + sg);
  ((uint4*)dp)[0] = u.q[0];
  ((uint4*)dp)[1] = u.q[1];
}

// 256 threads = 4 waves; each wave handles 8 tokens; block = 32 tokens.
// Per token: x->bf16 store, fp32 logits -> d_out tail, softmax, top-2.
// Counts aggregated in LDS, flushed as 16 padded global atomics per block.
__global__ __launch_bounds__(256) void router_kernel(
    const float* __restrict__ x, const float* __restrict__ rw,
    bfu* __restrict__ xb, float* __restrict__ logits,
    float* __restrict__ cw, int* __restrict__ eidx, int* __restrict__ meta) {
  __shared__ int hist[16];
  const int tid = threadIdx.x, lane = tid & 63, wave = tid >> 6;
  if (tid < 16) hist[tid] = 0;
  __syncthreads();

  for (int tk = 0; tk < 8; ++tk) {
    const int t = blockIdx.x * 32 + wave * 8 + tk;
    const float* xp = x + (size_t)t * D_ + lane * 16;
    float xv[16];
#pragma unroll
    for (int i = 0; i < 4; ++i) {
      float4 v = ((const float4*)xp)[i];
      xv[i * 4 + 0] = v.x; xv[i * 4 + 1] = v.y;
      xv[i * 4 + 2] = v.z; xv[i * 4 + 3] = v.w;
    }
    union { bfu b[16]; uint4 q[2]; } u;
#pragma unroll
    for (int i = 0; i < 16; ++i) u.b[i] = f2bf(xv[i]);
    uint4* xbp = (uint4*)(xb + (size_t)t * D_ + lane * 16);
    xbp[0] = u.q[0];
    xbp[1] = u.q[1];

    float l[16];
#pragma unroll
    for (int e = 0; e < 16; ++e) {
      const float* wp = rw + (size_t)e * D_ + lane * 16;
      float s = 0.f;
#pragma unroll
      for (int i = 0; i < 4; ++i) {
        float4 w = ((const float4*)wp)[i];
        s += xv[i * 4 + 0] * w.x + xv[i * 4 + 1] * w.y +
             xv[i * 4 + 2] * w.z + xv[i * 4 + 3] * w.w;
      }
#pragma unroll
      for (int off = 32; off; off >>= 1) s += __shfl_xor(s, off);
      l[e] = s;
    }
    float m = l[0];
#pragma unroll
    for (int e = 1; e < 16; ++e) m = fmaxf(m, l[e]);
    float p[16], sum = 0.f;
#pragma unroll
    for (int e = 0; e < 16; ++e) { p[e] = expf(l[e] - m); sum += p[e]; }
    int e0 = 0; float b0 = p[0];
#pragma unroll
    for (int e = 1; e < 16; ++e) if (p[e] > b0) { b0 = p[e]; e0 = e; }
    int e1 = -1; float b1 = -1.f;
#pragma unroll
    for (int e = 0; e < 16; ++e) if (e != e0 && p[e] > b1) { b1 = p[e]; e1 = e; }
    if (lane < 16) logits[(size_t)t * 16 + lane] = l[lane];
    if (lane == 0) {
      float inv = 1.f / sum;
      cw[t * 2 + 0] = b0 * inv;
      cw[t * 2 + 1] = b1 * inv;
      eidx[t * 2 + 0] = e0;
      eidx[t * 2 + 1] = e1;
      atomicAdd(&hist[e0], 1);
      atomicAdd(&hist[e1], 1);
    }
  }
  __syncthreads();
  if (tid < 16) atomicAdd(&meta[tid * 32], hist[tid]);
}

__global__ void scan_kernel(int* __restrict__ meta) {
  if (threadIdx.x != 0) return;
  int off = 0, nt = 0;
  for (int e = 0; e < 16; ++e) {
    meta[1024 + e] = off;
    int n = meta[e * 32];
    for (int r = 0; r < n; r += 128) {
      meta[1056 + nt] = e;
      meta[1600 + nt] = off + r;
      ++nt;
    }
    off += n;
  }
  meta[1040] = off;
  meta[1041] = nt;
}

// ballot-ranked placement: one cursor atomic per (expert, block)
__global__ __launch_bounds__(256) void perm_kernel(
    const int* __restrict__ eidx, int* __restrict__ meta, int* __restrict__ perm) {
  __shared__ int wcnt[4][16];  // per-wave per-expert count -> exclusive base
  __shared__ int bbase[16];    // block global base per expert
  const int tid = threadIdx.x, lane = tid & 63, wave = tid >> 6;
  const int p = blockIdx.x * 256 + tid;
  const int e = eidx[p];
  const unsigned long long lt = (lane == 63) ? ~0ull >> 1
                                             : (1ull << lane) - 1;
  int rank = 0;
#pragma unroll
  for (int q = 0; q < 16; ++q) {
    unsigned long long m = __ballot(e == q);
    if (e == q) rank = __popcll(m & lt);
    if (lane == 0) wcnt[wave][q] = __popcll(m);
  }
  __syncthreads();
  if (tid < 16) {
    int s = 0;
#pragma unroll
    for (int w = 0; w < 4; ++w) { int c = wcnt[w][tid]; wcnt[w][tid] = s; s += c; }
    bbase[tid] = atomicAdd(&meta[512 + tid * 32], s);
  }
  __syncthreads();
  perm[meta[1024 + e] + bbase[e] + wcnt[wave][e] + rank] = p;
}

// grouped gate/up GEMM: h[p, f] = silu(x@Wg) * (x@Wu), 128x128 tile, BK=32
__global__ __launch_bounds__(256, 2) void gateup_kernel(
    const bfu* __restrict__ xb, const bfu* __restrict__ wg,
    const bfu* __restrict__ wu, bfu* __restrict__ h,
    const int* __restrict__ perm, const int* __restrict__ meta) {
  __shared__ bfu As[128 * 32];
  __shared__ bfu Bg[128 * 32];
  __shared__ bfu Bu[128 * 32];
  __shared__ int rowtok[128];

  const int tile = blockIdx.y;
  if (tile >= meta[1041]) return;
  const int e = meta[1056 + tile];
  const int row0 = meta[1600 + tile];
  const int nvalid = meta[1025 + e] - row0;
  const int n0 = blockIdx.x * 128;
  const int tid = threadIdx.x, lane = tid & 63, wave = tid >> 6;

  if (tid < 128) {
    int r = tid < nvalid ? tid : (nvalid - 1);
    rowtok[tid] = perm[row0 + r] >> 1;
  }
  __syncthreads();

  const int ldr = wave * 32 + (lane >> 2);
  const int kseg = (lane & 3) * 8;
  const bfu* ap1 = xb + (size_t)rowtok[ldr] * D_ + kseg;
  const bfu* ap2 = xb + (size_t)rowtok[ldr + 16] * D_ + kseg;
  const size_t wb = (size_t)e * F_ * D_;
  const bfu* gp1 = wg + wb + (size_t)(n0 + ldr) * D_ + kseg;
  const bfu* gp2 = gp1 + (size_t)16 * D_;
  const bfu* up1 = wu + wb + (size_t)(n0 + ldr) * D_ + kseg;
  const bfu* up2 = up1 + (size_t)16 * D_;
  bfu* al1 = As + (wave * 32) * 32;
  bfu* al2 = As + (wave * 32 + 16) * 32;
  bfu* gl1 = Bg + (wave * 32) * 32;
  bfu* gl2 = Bg + (wave * 32 + 16) * 32;
  bfu* ul1 = Bu + (wave * 32) * 32;
  bfu* ul2 = Bu + (wave * 32 + 16) * 32;

  const int wm = (wave >> 1) * 64, wn = (wave & 1) * 64;
  const int fro = (lane & 15) * 32 + (lane >> 4) * 8;
  const bf16x8* afp = (const bf16x8*)(As + wm * 32 + fro);
  const bf16x8* bgp = (const bf16x8*)(Bg + wn * 32 + fro);
  const bf16x8* bup = (const bf16x8*)(Bu + wn * 32 + fro);

  floatx4 accg[4][4] = {};
  floatx4 accu[4][4] = {};

  for (int k0 = 0; k0 < D_; k0 += 32) {
    gload16(ap1 + k0, al1);
    gload16(ap2 + k0, al2);
    gload16(gp1 + k0, gl1);
    gload16(gp2 + k0, gl2);
    gload16(up1 + k0, ul1);
    gload16(up2 + k0, ul2);
    __syncthreads();
    bf16x8 af[4], bgf[4], buf_[4];
#pragma unroll
    for (int i = 0; i < 4; ++i) {
      af[i] = afp[i * 64];
      bgf[i] = bgp[i * 64];
      buf_[i] = bup[i * 64];
    }
#pragma unroll
    for (int mi = 0; mi < 4; ++mi)
#pragma unroll
      for (int ni = 0; ni < 4; ++ni) {
        accg[mi][ni] = __builtin_amdgcn_mfma_f32_16x16x32_bf16(
            af[mi], bgf[ni], accg[mi][ni], 0, 0, 0);
        accu[mi][ni] = __builtin_amdgcn_mfma_f32_16x16x32_bf16(
            af[mi], buf_[ni], accu[mi][ni], 0, 0, 0);
      }
    __syncthreads();
  }

  // epilogue: silu(g)*u -> bf16, repack 16x64 slabs through LDS for 16B stores
  bfu* slab = As + wave * 1024;  // wave-private 16x64 bf16
  const int sq = lane >> 4, sc = lane & 15;
  const int orow = lane >> 2, osg = (lane & 3) * 16;
#pragma unroll
  for (int mi = 0; mi < 4; ++mi) {
    __syncthreads();
#pragma unroll
    for (int ni = 0; ni < 4; ++ni) {
      floatx4 g = accg[mi][ni], v = accu[mi][ni];
#pragma unroll
      for (int i = 0; i < 4; ++i) {
        float gv = g[i];
        float hv = (gv / (1.f + __expf(-gv))) * v[i];
        slab[(sq * 4 + i) * 64 + ni * 16 + sc] = f2bf(hv);
      }
    }
    __syncthreads();
    const int prow = wm + mi * 16 + orow;
    if (prow < nvalid) {
      bfu* hp = h + (size_t)(row0 + prow) * F_ + (n0 + wn + osg);
      uint4 q0 = *(const uint4*)(slab + orow * 64 + osg);
      uint4 q1 = *(const uint4*)(slab + orow * 64 + osg + 8);
      ((uint4*)hp)[0] = q0;
      ((uint4*)hp)[1] = q1;
    }
  }
}

// grouped down GEMM: out[tok, d] += w * (h @ Wd), atomic scatter
__global__ __launch_bounds__(256, 2) void down_kernel(
    const bfu* __restrict__ h, const bfu* __restrict__ wd,
    float* __restrict__ out, const float* __restrict__ cw,
    const int* __restrict__ perm, const int* __restrict__ meta) {
  __shared__ bfu As[128 * 32];
  __shared__ bfu Bs[128 * 32];
  __shared__ int rtok[128];
  __shared__ float rwt[128];

  const int tile = blockIdx.y;
  if (tile >= meta[1041]) return;
  const int e = meta[1056 + tile];
  const int row0 = meta[1600 + tile];
  const int nvalid = meta[1025 + e] - row0;
  const int n0 = blockIdx.x * 128;
  const int tid = threadIdx.x, lane = tid & 63, wave = tid >> 6;

  if (tid < 128) {
    if (tid < nvalid) {
      int pr = perm[row0 + tid];
      rtok[tid] = pr >> 1;
      rwt[tid] = cw[pr];
    } else {
      rtok[tid] = 0;
      rwt[tid] = 0.f;
    }
  }
  __syncthreads();

  const int ldr = wave * 32 + (lane >> 2);
  const int kseg = (lane & 3) * 8;
  const int r1 = min(ldr, nvalid - 1);
  const int r2 = min(ldr + 16, nvalid - 1);
  const bfu* ap1 = h + (size_t)(row0 + r1) * F_ + kseg;
  const bfu* ap2 = h + (size_t)(row0 + r2) * F_ + kseg;
  const bfu* bp1 = wd + (size_t)e * D_ * F_ + (size_t)(n0 + ldr) * F_ + kseg;
  const bfu* bp2 = bp1 + (size_t)16 * F_;
  bfu* al1 = As + (wave * 32) * 32;
  bfu* al2 = As + (wave * 32 + 16) * 32;
  bfu* bl1 = Bs + (wave * 32) * 32;
  bfu* bl2 = Bs + (wave * 32 + 16) * 32;

  const int wm = (wave >> 1) * 64, wn = (wave & 1) * 64;
  const int fro = (lane & 15) * 32 + (lane >> 4) * 8;
  const bf16x8* afp = (const bf16x8*)(As + wm * 32 + fro);
  const bf16x8* bfp = (const bf16x8*)(Bs + wn * 32 + fro);

  floatx4 acc[4][4] = {};
  for (int k0 = 0; k0 < F_; k0 += 32) {
    gload16(ap1 + k0, al1);
    gload16(ap2 + k0, al2);
    gload16(bp1 + k0, bl1);
    gload16(bp2 + k0, bl2);
    __syncthreads();
    bf16x8 af[4], bf_[4];
#pragma unroll
    for (int i = 0; i < 4; ++i) { af[i] = afp[i * 64]; bf_[i] = bfp[i * 64]; }
#pragma unroll
    for (int mi = 0; mi < 4; ++mi)
#pragma unroll
      for (int ni = 0; ni < 4; ++ni)
        acc[mi][ni] = __builtin_amdgcn_mfma_f32_16x16x32_bf16(
            af[mi], bf_[ni], acc[mi][ni], 0, 0, 0);
    __syncthreads();
  }

  const int sq = lane >> 4, sc = lane & 15;
#pragma unroll
  for (int mi = 0; mi < 4; ++mi) {
#pragma unroll
    for (int i = 0; i < 4; ++i) {
      const int r = wm + mi * 16 + sq * 4 + i;
      const float w = rwt[r];
      if (w != 0.f) {
        const int tok = rtok[r];
        float* op = out + (size_t)tok * D_ + n0 + wn + sc;
#pragma unroll
        for (int ni = 0; ni < 4; ++ni)
          atomicAdd(op + ni * 16, w * acc[mi][ni][i]);
      }
    }
  }
}

extern "C" void kernel_launch(void* const* d_in, const int* in_sizes, int n_in,
                              void* d_out, int out_size, void* d_ws, size_t ws_size,
                              hipStream_t stream) {
  const float* x  = (const float*)d_in[0];
  const float* rw = (const float*)d_in[1];
  const float* gw = (const float*)d_in[2];
  const float* uw = (const float*)d_in[3];
  const float* dw = (const float*)d_in[4];
  float* out = (float*)d_out;
  float* logits = out + (size_t)T_ * D_;

  char* ws = (char*)d_ws;
  bfu* xb  = (bfu*)(ws + O_XB);
  bfu* wgt = (bfu*)(ws + O_WG);
  bfu* wut = (bfu*)(ws + O_WU);
  bfu* wdt = (bfu*)(ws + O_WD);
  bfu* hb  = (bfu*)(ws + O_H);
  float* cwp = (float*)(ws + O_CW);
  int* eip  = (int*)(ws + O_EI);
  int* perm = (int*)(ws + O_PM);
  int* meta = (int*)(ws + O_MT);

  // zero out accumulator region + padded counts/cursors (first 1024 ints)
  hipMemsetAsync(out, 0, (size_t)T_ * D_ * sizeof(float), stream);
  hipMemsetAsync(meta, 0, 4096, stream);

  // weight transpose+cast: gate/up [D,F]->[F,D], down [F,D]->[D,F]
  transpose_cast_kernel<<<dim3(F_ / 64, D_ / 64, E_), 256, 0, stream>>>(gw, wgt, D_, F_);
  transpose_cast_kernel<<<dim3(F_ / 64, D_ / 64, E_), 256, 0, stream>>>(uw, wut, D_, F_);
  transpose_cast_kernel<<<dim3(D_ / 64, F_ / 64, E_), 256, 0, stream>>>(dw, wdt, F_, D_);

  router_kernel<<<T_ / 32, 256, 0, stream>>>(x, rw, xb, logits, cwp, eip, meta);
  scan_kernel<<<1, 64, 0, stream>>>(meta);
  perm_kernel<<<P_ / 256, 256, 0, stream>>>(eip, meta, perm);

  gateup_kernel<<<dim3(F_ / 128, MAXTILES), 256, 0, stream>>>(xb, wgt, wut, hb, perm, meta);
  down_kernel<<<dim3(D_ / 128, MAXTILES), 256, 0, stream>>>(hb, wdt, out, cwp, perm, meta);
}